// Round 9
// baseline (189.969 us; speedup 1.0000x reference)
//
#include <hip/hip_runtime.h>

// LinearAttention fused pipeline, MI355X gfx950. Round 9.
// Design shift: NO LDS staging for weights (L2-hot, gathered per-fragment
// as global_load_dwordx4 into VGPRs), x-tile staged in LDS ONCE per block,
// K-loop has ZERO barriers. 2 blocks/CU (16 waves) via small LDS +
// __launch_bounds__(512,4). Pure compiler scheduling, no inline asm.
// k_init:      w_qkv->wh f16, w_out->wouth f16, zero kv/den
// k_transpose: x[b][c][n] f32 -> xh[b][n][c] f16
// k_kv:        k'=elu1(Wk.x), v=Wv.x; kv/den in-register -> atomics
// k_fused2:    Q=elu1(Wq.x)*s*1024 -> Q overlays x LDS -> out=wouth.Q -> LN

#define NB 16
#define NC 256
#define NN 4096
#define LN_EPS 1e-5f
#define IOSCALE (1.0f/1024.0f)

typedef _Float16 f16;
typedef _Float16 f16x8 __attribute__((ext_vector_type(8)));
typedef _Float16 f16x4v __attribute__((ext_vector_type(4)));
typedef float f32x4 __attribute__((ext_vector_type(4)));

__device__ __forceinline__ float elu1(float x) {
  return x > 0.f ? x + 1.f : __expf(x);
}
#define MFMA16 __builtin_amdgcn_mfma_f32_16x16x32_f16

__global__ __launch_bounds__(256) void k_init(const float* __restrict__ wqkv,
                                              const float* __restrict__ wout,
                                              f16* __restrict__ wh,
                                              f16* __restrict__ wouth,
                                              float* __restrict__ kvden) {
  int i = blockIdx.x * 256 + threadIdx.x;
  wh[i] = (f16)wqkv[i];
  if (i < 65536) wouth[i] = (f16)wout[i];
  if (i < 8192) kvden[i] = 0.f;
}

// x[b][c][n] f32 -> xh[b][n][c] f16. 64x64 tiles via padded LDS.
__global__ __launch_bounds__(256) void k_transpose(const float* __restrict__ x,
                                                   f16* __restrict__ xh) {
  __shared__ float t[64 * 65];
  const int b = blockIdx.z, c0 = blockIdx.y * 64, n0 = blockIdx.x * 64;
  const int tid = threadIdx.x;
#pragma unroll
  for (int i = 0; i < 4; ++i) {
    int lin = tid + i * 256;
    int r = lin >> 4;
    int cg = lin & 15;
    const float4 v = *reinterpret_cast<const float4*>(
        &x[((size_t)(b * NC + c0 + r)) * NN + n0 + cg * 4]);
    t[r * 65 + cg * 4 + 0] = v.x;
    t[r * 65 + cg * 4 + 1] = v.y;
    t[r * 65 + cg * 4 + 2] = v.z;
    t[r * 65 + cg * 4 + 3] = v.w;
  }
  __syncthreads();
#pragma unroll
  for (int i = 0; i < 4; ++i) {
    int lin = tid + i * 256;
    int nr = lin >> 4;
    int cg = lin & 15;
    f16x4v h;
    h[0] = (f16)t[(cg * 4 + 0) * 65 + nr];
    h[1] = (f16)t[(cg * 4 + 1) * 65 + nr];
    h[2] = (f16)t[(cg * 4 + 2) * 65 + nr];
    h[3] = (f16)t[(cg * 4 + 3) * 65 + nr];
    *reinterpret_cast<f16x4v*>(&xh[((size_t)(b * NN + n0 + nr)) * NC + c0 + cg * 4]) = h;
  }
}

// kv/den. Block: 64n x 256ch (k&v). 512 thr = 8 waves = 4 cg x 2 ng.
// Wave = 64ch x 32n, acc = 16 f32x4. W-fragments gathered from L2.
__global__ __launch_bounds__(512, 4) void k_kv(const f16* __restrict__ xh,
                                               const f16* __restrict__ wh,
                                               float* __restrict__ kv,
                                               float* __restrict__ den) {
  __shared__ __align__(16) f16 Xt[64 * 264];   // 33.8 KB padded
  const int b = blockIdx.y;
  const int n0 = blockIdx.x * 64;
  const int tid = threadIdx.x;
  const int lane = tid & 63;
  const int wv = tid >> 6;
  const int cg = wv >> 1, ng = wv & 1;
  const int l15 = lane & 15, lg = lane >> 4;

  // ---- stage x-tile once (coalesced b128 -> padded LDS rows) ----
#pragma unroll
  for (int i = 0; i < 4; ++i) {
    const int idx = i * 512 + tid;       // 0..2047
    const int row = idx >> 5, u = idx & 31;
    const f16x8 h = *(const f16x8*)(xh + ((size_t)(b * NN + n0 + row)) * NC + u * 8);
    *reinterpret_cast<f16x8*>(&Xt[row * 264 + u * 8]) = h;
  }
  __syncthreads();

  // ---- barrier-free K-loop: W gathered from L2, x from LDS ----
  f32x4 kacc[4][2] = {};
  f32x4 vacc[4][2] = {};
  const f16* wk = wh + (size_t)(256 + cg * 64 + l15) * NC;
  const f16* wvp = wh + (size_t)(512 + cg * 64 + l15) * NC;
#pragma unroll
  for (int s = 0; s < 8; ++s) {
    const int k0 = s * 32 + lg * 8;
    f16x8 bx[2];
#pragma unroll
    for (int f = 0; f < 2; ++f)
      bx[f] = *(const f16x8*)(&Xt[(ng * 32 + f * 16 + l15) * 264 + k0]);
#pragma unroll
    for (int m = 0; m < 4; ++m) {
      const f16x8 ak = *(const f16x8*)(wk + (size_t)(m * 16) * NC + k0);
      const f16x8 av = *(const f16x8*)(wvp + (size_t)(m * 16) * NC + k0);
#pragma unroll
      for (int f = 0; f < 2; ++f) {
        kacc[m][f] = MFMA16(ak, bx[f], kacc[m][f], 0, 0, 0);
        vacc[m][f] = MFMA16(av, bx[f], vacc[m][f], 0, 0, 0);
      }
    }
  }

  // ---- per-channel reduction over n: shuffle across l15, atomics ----
#pragma unroll
  for (int m = 0; m < 4; ++m) {
#pragma unroll
    for (int j = 0; j < 4; ++j) {
      float a = 0.f, d = 0.f;
#pragma unroll
      for (int f = 0; f < 2; ++f) {
        const float kk = elu1(kacc[m][f][j]);
        a += kk * vacc[m][f][j];
        d += kk;
      }
      a += __shfl_xor(a, 1, 64);  d += __shfl_xor(d, 1, 64);
      a += __shfl_xor(a, 2, 64);  d += __shfl_xor(d, 2, 64);
      a += __shfl_xor(a, 4, 64);  d += __shfl_xor(d, 4, 64);
      a += __shfl_xor(a, 8, 64);  d += __shfl_xor(d, 8, 64);
      if (l15 == 0) {
        const int c = cg * 64 + m * 16 + lg * 4 + j;
        atomicAdd(&kv[b * NC + c], a);
        atomicAdd(&den[b * NC + c], d);
      }
    }
  }
}

// Fused GEMM1(q)+scale -> Q overlays x LDS -> GEMM2 -> LN.
// 512 thr = 8 waves = 4 cg x 2 ng; W from L2, barrier-free K-loops.
__global__ __launch_bounds__(512, 4) void k_fused2(const f16* __restrict__ xh,
                                                   const f16* __restrict__ wh,
                                                   const f16* __restrict__ wouth,
                                                   const float* __restrict__ kv,
                                                   const float* __restrict__ den,
                                                   const float* __restrict__ gamma,
                                                   const float* __restrict__ beta,
                                                   float* __restrict__ out) {
  __shared__ __align__(16) f16 XQ[64 * 264];   // x-tile, later Q
  __shared__ float s1024[256];
  __shared__ float red1[4][64], red2[4][64], smu[64], srs[64];
  const int b = blockIdx.y;
  const int n0 = blockIdx.x * 64;
  const int tid = threadIdx.x;
  const int lane = tid & 63;
  const int wv = tid >> 6;
  const int cg = wv >> 1, ng = wv & 1;
  const int l15 = lane & 15, lg = lane >> 4;

  // ---- stage x-tile + s1024 ----
#pragma unroll
  for (int i = 0; i < 4; ++i) {
    const int idx = i * 512 + tid;
    const int row = idx >> 5, u = idx & 31;
    const f16x8 h = *(const f16x8*)(xh + ((size_t)(b * NN + n0 + row)) * NC + u * 8);
    *reinterpret_cast<f16x8*>(&XQ[row * 264 + u * 8]) = h;
  }
  if (tid < 256)
    s1024[tid] = kv[b * NC + tid] / fmaxf(den[b * NC + tid], 1e-6f) * 1024.0f;
  __syncthreads();

  // ---- GEMM1: qT = Wq . x^T ----
  f32x4 acc[4][2] = {};
  {
    const f16* wq = wh + (size_t)(cg * 64 + l15) * NC;
#pragma unroll
    for (int s = 0; s < 8; ++s) {
      const int k0 = s * 32 + lg * 8;
      f16x8 bx[2];
#pragma unroll
      for (int f = 0; f < 2; ++f)
        bx[f] = *(const f16x8*)(&XQ[(ng * 32 + f * 16 + l15) * 264 + k0]);
#pragma unroll
      for (int m = 0; m < 4; ++m) {
        const f16x8 aq = *(const f16x8*)(wq + (size_t)(m * 16) * NC + k0);
#pragma unroll
        for (int f = 0; f < 2; ++f)
          acc[m][f] = MFMA16(aq, bx[f], acc[m][f], 0, 0, 0);
      }
    }
  }
  __syncthreads();   // all x reads done before overlaying Q

  // ---- Q publish: Q[n][c] = elu1(q)*s*1024 (overlays XQ) ----
#pragma unroll
  for (int m = 0; m < 4; ++m) {
    const int ch = cg * 64 + m * 16 + lg * 4;
    const float4 sv = *reinterpret_cast<const float4*>(&s1024[ch]);
#pragma unroll
    for (int f = 0; f < 2; ++f) {
      const int n = ng * 32 + f * 16 + l15;
      f16x4v h;
      h[0] = (f16)(elu1(acc[m][f][0]) * sv.x);
      h[1] = (f16)(elu1(acc[m][f][1]) * sv.y);
      h[2] = (f16)(elu1(acc[m][f][2]) * sv.z);
      h[3] = (f16)(elu1(acc[m][f][3]) * sv.w);
      *reinterpret_cast<f16x4v*>(&XQ[n * 264 + ch]) = h;
    }
  }
  __syncthreads();

  // ---- GEMM2: out = wouth . Q ----
  f32x4 acc2[4][2] = {};
  {
    const f16* wo = wouth + (size_t)(cg * 64 + l15) * NC;
#pragma unroll
    for (int s = 0; s < 8; ++s) {
      const int k0 = s * 32 + lg * 8;
      f16x8 bq[2];
#pragma unroll
      for (int f = 0; f < 2; ++f)
        bq[f] = *(const f16x8*)(&XQ[(ng * 32 + f * 16 + l15) * 264 + k0]);
#pragma unroll
      for (int m = 0; m < 4; ++m) {
        const f16x8 ao = *(const f16x8*)(wo + (size_t)(m * 16) * NC + k0);
#pragma unroll
        for (int f = 0; f < 2; ++f)
          acc2[m][f] = MFMA16(ao, bq[f], acc2[m][f], 0, 0, 0);
      }
    }
  }

  // ---- LayerNorm over o (256) per column n ----
  float s1[2] = {0, 0}, s2[2] = {0, 0};
#pragma unroll
  for (int f = 0; f < 2; ++f)
#pragma unroll
    for (int m = 0; m < 4; ++m)
#pragma unroll
      for (int j = 0; j < 4; ++j) {
        const float v = acc2[m][f][j];
        s1[f] += v;
        s2[f] += v * v;
      }
#pragma unroll
  for (int f = 0; f < 2; ++f) {
    s1[f] += __shfl_xor(s1[f], 16, 64);
    s1[f] += __shfl_xor(s1[f], 32, 64);
    s2[f] += __shfl_xor(s2[f], 16, 64);
    s2[f] += __shfl_xor(s2[f], 32, 64);
  }
  if (lane < 16) {
#pragma unroll
    for (int f = 0; f < 2; ++f) {
      const int col = ng * 32 + f * 16 + lane;
      red1[cg][col] = s1[f];
      red2[cg][col] = s2[f];
    }
  }
  __syncthreads();
  if (tid < 64) {
    const float a1 = red1[0][tid] + red1[1][tid] + red1[2][tid] + red1[3][tid];
    const float a2 = red2[0][tid] + red2[1][tid] + red2[2][tid] + red2[3][tid];
    const float mu = a1 * (IOSCALE / 256.f);
    const float e2 = a2 * (IOSCALE * IOSCALE / 256.f);
    smu[tid] = mu;
    srs[tid] = rsqrtf(e2 - mu * mu + LN_EPS);
  }
  __syncthreads();
#pragma unroll
  for (int m = 0; m < 4; ++m) {
    const int ob = cg * 64 + m * 16 + lg * 4;
#pragma unroll
    for (int j = 0; j < 4; ++j) {
      const int o = ob + j;
      const float g = gamma[o], be = beta[o];
#pragma unroll
      for (int f = 0; f < 2; ++f) {
        const int col = ng * 32 + f * 16 + l15;
        const float v = acc2[m][f][j] * IOSCALE;
        out[((size_t)(b * NC + o)) * NN + n0 + col] = (v - smu[col]) * srs[col] * g + be;
      }
    }
  }
}

extern "C" void kernel_launch(void* const* d_in, const int* in_sizes, int n_in,
                              void* d_out, int out_size, void* d_ws, size_t ws_size,
                              hipStream_t stream) {
  const float* x = (const float*)d_in[0];
  const float* w_qkv = (const float*)d_in[1];
  const float* w_out = (const float*)d_in[2];
  const float* ln_g = (const float*)d_in[3];
  const float* ln_b = (const float*)d_in[4];
  float* out = (float*)d_out;

  char* wsb = (char*)d_ws;
  const size_t OFF_WH = 0;                        // 768*256*2 = 393216
  const size_t OFF_WOUTH = 393216;                // 256*256*2 = 131072
  const size_t OFF_XH = OFF_WOUTH + 131072;       // 32 MiB
  const size_t OFF_KV = OFF_XH + 33554432;        // 16 KiB
  const size_t OFF_DEN = OFF_KV + 16384;          // 16 KiB

  f16* wh = (f16*)(wsb + OFF_WH);
  f16* wouth = (f16*)(wsb + OFF_WOUTH);
  f16* xh = (f16*)(wsb + OFF_XH);
  float* kv = (float*)(wsb + OFF_KV);
  float* den = (float*)(wsb + OFF_DEN);

  k_init<<<768, 256, 0, stream>>>(w_qkv, w_out, wh, wouth, kv);
  k_transpose<<<dim3(64, 4, 16), 256, 0, stream>>>(x, xh);
  k_kv<<<dim3(64, 16), 512, 0, stream>>>(xh, wh, kv, den);
  k_fused2<<<dim3(64, 16), 512, 0, stream>>>(xh, wh, wouth, kv, den, ln_g, ln_b, out);
}

// Round 10
// 87.763 us; speedup vs baseline: 2.1646x; 2.1646x over previous
//
#include <hip/hip_runtime.h>

// LinearAttention fused pipeline, MI355X gfx950. Round 10.
// Mega-block design: 1024 thr / 16 waves / 1 block/CU (50% occupancy),
// n-tile 128 -> half the W-restage L2 traffic and half the barriers of the
// 64n/8-wave configs at the SAME waves-per-SIMD. W staged via gload16
// (linear dest + pre-swizzled per-lane source + matching swizzled reads,
// 2-way max bank aliasing). __syncthreads-only sync (verified fencing).
// k_init:      w_qkv->wh f16, w_out->wouth f16, zero kv/den
// k_transpose: x[b][c][n] f32 -> xh[b][n][c] f16
// k_kv:        k'=elu1(Wk.x), v=Wv.x; kv/den in-register -> atomics
// k_fused2:    Q=elu1(Wq.x)*s*1024 overlays x-LDS -> out=wouth.Q -> LN

#define NB 16
#define NC 256
#define NN 4096
#define LN_EPS 1e-5f
#define IOSCALE (1.0f/1024.0f)

typedef _Float16 f16;
typedef _Float16 f16x8 __attribute__((ext_vector_type(8)));
typedef _Float16 f16x4v __attribute__((ext_vector_type(4)));
typedef float f32x4 __attribute__((ext_vector_type(4)));

typedef __attribute__((address_space(1))) const unsigned int* as1cu32;
typedef __attribute__((address_space(3))) unsigned int* as3u32;

__device__ __forceinline__ void gload16(const void* g, void* l) {
  __builtin_amdgcn_global_load_lds((as1cu32)g, (as3u32)l, 16, 0, 0);
}
__device__ __forceinline__ float elu1(float x) {
  return x > 0.f ? x + 1.f : __expf(x);
}
#define MFMA16 __builtin_amdgcn_mfma_f32_16x16x32_f16

__global__ __launch_bounds__(256) void k_init(const float* __restrict__ wqkv,
                                              const float* __restrict__ wout,
                                              f16* __restrict__ wh,
                                              f16* __restrict__ wouth,
                                              float* __restrict__ kvden) {
  int i = blockIdx.x * 256 + threadIdx.x;
  wh[i] = (f16)wqkv[i];
  if (i < 65536) wouth[i] = (f16)wout[i];
  if (i < 8192) kvden[i] = 0.f;
}

// x[b][c][n] f32 -> xh[b][n][c] f16. 64x64 tiles via padded LDS.
__global__ __launch_bounds__(256) void k_transpose(const float* __restrict__ x,
                                                   f16* __restrict__ xh) {
  __shared__ float t[64 * 65];
  const int b = blockIdx.z, c0 = blockIdx.y * 64, n0 = blockIdx.x * 64;
  const int tid = threadIdx.x;
#pragma unroll
  for (int i = 0; i < 4; ++i) {
    int lin = tid + i * 256;
    int r = lin >> 4;
    int cg = lin & 15;
    const float4 v = *reinterpret_cast<const float4*>(
        &x[((size_t)(b * NC + c0 + r)) * NN + n0 + cg * 4]);
    t[r * 65 + cg * 4 + 0] = v.x;
    t[r * 65 + cg * 4 + 1] = v.y;
    t[r * 65 + cg * 4 + 2] = v.z;
    t[r * 65 + cg * 4 + 3] = v.w;
  }
  __syncthreads();
#pragma unroll
  for (int i = 0; i < 4; ++i) {
    int lin = tid + i * 256;
    int nr = lin >> 4;
    int cg = lin & 15;
    f16x4v h;
    h[0] = (f16)t[(cg * 4 + 0) * 65 + nr];
    h[1] = (f16)t[(cg * 4 + 1) * 65 + nr];
    h[2] = (f16)t[(cg * 4 + 2) * 65 + nr];
    h[3] = (f16)t[(cg * 4 + 3) * 65 + nr];
    *reinterpret_cast<f16x4v*>(&xh[((size_t)(b * NN + n0 + nr)) * NC + c0 + cg * 4]) = h;
  }
}

// kv/den. Block: 128n x 256ch(k&v). 1024 thr = 16 waves = 4 ng x 4 cg.
// Xt staged once (swizzled: unit^(row&31)); Bt double-buffered per BK=32
// chunk (swizzled: unit^((row>>1)&3)).
__global__ __launch_bounds__(1024, 4) void k_kv(const f16* __restrict__ xh,
                                                const f16* __restrict__ wh,
                                                float* __restrict__ kv,
                                                float* __restrict__ den) {
  __shared__ __align__(16) f16 Xt[128 * 256];     // 64 KB
  __shared__ __align__(16) f16 Bt[2][512 * 32];   // 2 x 32 KB (k rows 0..255, v 256..511)
  const int b = blockIdx.y;
  const int n0 = blockIdx.x * 128;
  const int tid = threadIdx.x;
  const int lane = tid & 63;
  const int wv = tid >> 6;            // 0..15
  const int ng = wv >> 2, cg = wv & 3;
  const int l15 = lane & 15, lg = lane >> 4;

  // ---- stage Xt once: 64 gload16 instrs (2 rows each), 4 per wave ----
  {
    const int rsub = lane >> 5;       // 0..1
    const int u = lane & 31;          // 16B unit within 512B row
#pragma unroll
    for (int i = 0; i < 4; ++i) {
      const int inst = wv * 4 + i;    // 0..63
      const int row = inst * 2 + rsub;
      gload16(xh + ((size_t)(b * NN + n0 + row)) * NC + ((u ^ (row & 31)) * 8),
              &Xt[inst * 512]);
    }
  }

  // Bt chunk stage: 32 instrs (16 rows each), 2 per wave
  auto stageB = [&](int s, int bb) {
    const int c0 = s * 32;
    const int rsub = lane >> 2;       // 0..15
    const int u = lane & 3;           // 16B unit within 64B row
#pragma unroll
    for (int i = 0; i < 2; ++i) {
      const int inst = wv * 2 + i;    // 0..31
      const int row = inst * 16 + rsub;   // 0..511
      gload16(wh + (size_t)(256 + row) * NC + c0 + ((u ^ ((row >> 1) & 3)) * 8),
              &Bt[bb][inst * 512]);
    }
  };

  stageB(0, 0);
  __syncthreads();

  f32x4 kacc[2][4] = {};
  f32x4 vacc[2][4] = {};
  for (int s = 0; s < 8; ++s) {
    const int cb = s & 1;
    if (s < 7) stageB(s + 1, cb ^ 1);
    f16x8 a[2];
#pragma unroll
    for (int m = 0; m < 2; ++m) {
      const int R = ng * 32 + m * 16 + l15;
      const int U = s * 4 + lg;
      a[m] = *(const f16x8*)(&Xt[R * 256 + ((U ^ (R & 31)) * 8)]);
    }
#pragma unroll
    for (int f = 0; f < 4; ++f) {
      const int Rk = cg * 64 + f * 16 + l15;
      const f16x8 bk = *(const f16x8*)(&Bt[cb][Rk * 32 + ((lg ^ ((Rk >> 1) & 3)) * 8)]);
      const int Rv = 256 + Rk;
      const f16x8 bv = *(const f16x8*)(&Bt[cb][Rv * 32 + ((lg ^ ((Rv >> 1) & 3)) * 8)]);
#pragma unroll
      for (int m = 0; m < 2; ++m) {
        kacc[m][f] = MFMA16(a[m], bk, kacc[m][f], 0, 0, 0);
        vacc[m][f] = MFMA16(a[m], bv, vacc[m][f], 0, 0, 0);
      }
    }
    if (s < 7) __syncthreads();
  }

  // D[row=n][col=ch]: reduce over n (m,j,lg), atomics per channel
  float pkv[4] = {0.f, 0.f, 0.f, 0.f}, pden[4] = {0.f, 0.f, 0.f, 0.f};
#pragma unroll
  for (int f = 0; f < 4; ++f)
#pragma unroll
    for (int m = 0; m < 2; ++m)
#pragma unroll
      for (int j = 0; j < 4; ++j) {
        const float kk = elu1(kacc[m][f][j]);
        pkv[f] += kk * vacc[m][f][j];
        pden[f] += kk;
      }
#pragma unroll
  for (int f = 0; f < 4; ++f) {
    pkv[f] += __shfl_xor(pkv[f], 16, 64);
    pkv[f] += __shfl_xor(pkv[f], 32, 64);
    pden[f] += __shfl_xor(pden[f], 16, 64);
    pden[f] += __shfl_xor(pden[f], 32, 64);
  }
  if (lane < 16) {
#pragma unroll
    for (int f = 0; f < 4; ++f) {
      const int c = cg * 64 + f * 16 + lane;
      atomicAdd(&kv[b * NC + c], pkv[f]);
      atomicAdd(&den[b * NC + c], pden[f]);
    }
  }
}

// Fused GEMM1(q)+scale -> Q overlays x-LDS -> GEMM2 -> LN.
// 1024 thr = 16 waves = 4 cg x 4 ng, n-tile 128.
__global__ __launch_bounds__(1024, 4) void k_fused2(const f16* __restrict__ xh,
                                                    const f16* __restrict__ wh,
                                                    const f16* __restrict__ wouth,
                                                    const float* __restrict__ kv,
                                                    const float* __restrict__ den,
                                                    const float* __restrict__ gamma,
                                                    const float* __restrict__ beta,
                                                    float* __restrict__ out) {
  __shared__ __align__(16) f16 XQ[128 * 256];     // 64 KB: x, then Q overlay
  __shared__ __align__(16) f16 Wt[2][256 * 32];   // 2 x 16 KB (LN scratch overlay)
  __shared__ float s1024[256];
  const int b = blockIdx.y;
  const int n0 = blockIdx.x * 128;
  const int tid = threadIdx.x;
  const int lane = tid & 63;
  const int wv = tid >> 6;            // 0..15
  const int cg = wv & 3, ng = wv >> 2;
  const int l15 = lane & 15, lg = lane >> 4;

  // ---- stage x-tile (swizzled) + s1024 ----
  {
    const int rsub = lane >> 5;
    const int u = lane & 31;
#pragma unroll
    for (int i = 0; i < 4; ++i) {
      const int inst = wv * 4 + i;
      const int row = inst * 2 + rsub;
      gload16(xh + ((size_t)(b * NN + n0 + row)) * NC + ((u ^ (row & 31)) * 8),
              &XQ[inst * 512]);
    }
  }
  if (tid < 256)
    s1024[tid] = kv[b * NC + tid] / fmaxf(den[b * NC + tid], 1e-6f) * 1024.0f;

  // W chunk stage: 16 instrs (16 rows each), 1 per wave
  auto stageW = [&](const f16* __restrict__ W, int s, int bb) {
    const int c0 = s * 32;
    const int row = wv * 16 + (lane >> 2);
    const int u = lane & 3;
    gload16(W + (size_t)row * NC + c0 + ((u ^ ((row >> 1) & 3)) * 8),
            &Wt[bb][wv * 512]);
  };

  stageW(wh, 0, 0);
  __syncthreads();

  // ---- GEMM1: qT = Wq . x^T  (A = Wq frag, B = x frag) ----
  f32x4 acc[4][2] = {};
  for (int s = 0; s < 8; ++s) {
    const int cb = s & 1;
    if (s < 7) stageW(wh, s + 1, cb ^ 1);
    else stageW(wouth, 0, cb ^ 1);   // prefetch Wo chunk 0
    f16x8 a[4], bx[2];
#pragma unroll
    for (int m = 0; m < 4; ++m) {
      const int R = cg * 64 + m * 16 + l15;
      a[m] = *(const f16x8*)(&Wt[cb][R * 32 + ((lg ^ ((R >> 1) & 3)) * 8)]);
    }
#pragma unroll
    for (int f = 0; f < 2; ++f) {
      const int Rn = ng * 32 + f * 16 + l15;
      const int U = s * 4 + lg;
      bx[f] = *(const f16x8*)(&XQ[Rn * 256 + ((U ^ (Rn & 31)) * 8)]);
    }
#pragma unroll
    for (int m = 0; m < 4; ++m)
#pragma unroll
      for (int f = 0; f < 2; ++f)
        acc[m][f] = MFMA16(a[m], bx[f], acc[m][f], 0, 0, 0);
    __syncthreads();   // s<7: protect Wt swap; s==7: x reads done + Wo0 landed
  }

  // ---- Q publish (overlays XQ, same swizzle): Q[n][ch] = elu1(q)*s1024 ----
#pragma unroll
  for (int m = 0; m < 4; ++m) {
    const int ch = cg * 64 + m * 16 + lg * 4;
    const float4 sv = *reinterpret_cast<const float4*>(&s1024[ch]);
    const int u = ch >> 3;
#pragma unroll
    for (int f = 0; f < 2; ++f) {
      const int n = ng * 32 + f * 16 + l15;
      f16x4v h;
      h[0] = (f16)(elu1(acc[m][f][0]) * sv.x);
      h[1] = (f16)(elu1(acc[m][f][1]) * sv.y);
      h[2] = (f16)(elu1(acc[m][f][2]) * sv.z);
      h[3] = (f16)(elu1(acc[m][f][3]) * sv.w);
      *reinterpret_cast<f16x4v*>(&XQ[n * 256 + ((u ^ (n & 31)) * 8) + (ch & 7)]) = h;
    }
  }
  __syncthreads();

  // ---- GEMM2: out = wouth . Q  (A = Wo frag, B = Q frag) ----
  f32x4 acc2[4][2] = {};
  for (int s = 0; s < 8; ++s) {
    const int cb = s & 1;
    if (s < 7) stageW(wouth, s + 1, cb ^ 1);
    f16x8 a[4], bq[2];
#pragma unroll
    for (int m = 0; m < 4; ++m) {
      const int R = cg * 64 + m * 16 + l15;
      a[m] = *(const f16x8*)(&Wt[cb][R * 32 + ((lg ^ ((R >> 1) & 3)) * 8)]);
    }
#pragma unroll
    for (int f = 0; f < 2; ++f) {
      const int n = ng * 32 + f * 16 + l15;
      const int U = s * 4 + lg;
      bq[f] = *(const f16x8*)(&XQ[n * 256 + ((U ^ (n & 31)) * 8)]);
    }
#pragma unroll
    for (int m = 0; m < 4; ++m)
#pragma unroll
      for (int f = 0; f < 2; ++f)
        acc2[m][f] = MFMA16(a[m], bq[f], acc2[m][f], 0, 0, 0);
    if (s < 7) __syncthreads();
  }

  // ---- LayerNorm over o (256) per column n; scratch overlays Wt ----
  float* red1 = (float*)(&Wt[0][0]);   // [4][128]
  float* red2 = red1 + 512;
  float* smu = red2 + 512;             // [128]
  float* srs = smu + 128;
  float s1[2] = {0, 0}, s2[2] = {0, 0};
#pragma unroll
  for (int f = 0; f < 2; ++f)
#pragma unroll
    for (int m = 0; m < 4; ++m)
#pragma unroll
      for (int j = 0; j < 4; ++j) {
        const float v = acc2[m][f][j];
        s1[f] += v;
        s2[f] += v * v;
      }
#pragma unroll
  for (int f = 0; f < 2; ++f) {
    s1[f] += __shfl_xor(s1[f], 16, 64);
    s1[f] += __shfl_xor(s1[f], 32, 64);
    s2[f] += __shfl_xor(s2[f], 16, 64);
    s2[f] += __shfl_xor(s2[f], 32, 64);
  }
  __syncthreads();   // all GEMM2 LDS reads retired before Wt overlay
  if (lane < 16) {
#pragma unroll
    for (int f = 0; f < 2; ++f) {
      const int col = ng * 32 + f * 16 + lane;
      red1[cg * 128 + col] = s1[f];
      red2[cg * 128 + col] = s2[f];
    }
  }
  __syncthreads();
  if (tid < 128) {
    const float a1 = red1[tid] + red1[128 + tid] + red1[256 + tid] + red1[384 + tid];
    const float a2 = red2[tid] + red2[128 + tid] + red2[256 + tid] + red2[384 + tid];
    const float mu = a1 * (IOSCALE / 256.f);
    const float e2 = a2 * (IOSCALE * IOSCALE / 256.f);
    smu[tid] = mu;
    srs[tid] = rsqrtf(e2 - mu * mu + LN_EPS);
  }
  __syncthreads();
#pragma unroll
  for (int m = 0; m < 4; ++m) {
    const int ob = cg * 64 + m * 16 + lg * 4;
#pragma unroll
    for (int j = 0; j < 4; ++j) {
      const int o = ob + j;
      const float g = gamma[o], be = beta[o];
#pragma unroll
      for (int f = 0; f < 2; ++f) {
        const int col = ng * 32 + f * 16 + l15;
        const float v = acc2[m][f][j] * IOSCALE;
        out[((size_t)(b * NC + o)) * NN + n0 + col] = (v - smu[col]) * srs[col] * g + be;
      }
    }
  }
}

extern "C" void kernel_launch(void* const* d_in, const int* in_sizes, int n_in,
                              void* d_out, int out_size, void* d_ws, size_t ws_size,
                              hipStream_t stream) {
  const float* x = (const float*)d_in[0];
  const float* w_qkv = (const float*)d_in[1];
  const float* w_out = (const float*)d_in[2];
  const float* ln_g = (const float*)d_in[3];
  const float* ln_b = (const float*)d_in[4];
  float* out = (float*)d_out;

  char* wsb = (char*)d_ws;
  const size_t OFF_WH = 0;                        // 768*256*2 = 393216
  const size_t OFF_WOUTH = 393216;                // 256*256*2 = 131072
  const size_t OFF_XH = OFF_WOUTH + 131072;       // 32 MiB
  const size_t OFF_KV = OFF_XH + 33554432;        // 16 KiB
  const size_t OFF_DEN = OFF_KV + 16384;          // 16 KiB

  f16* wh = (f16*)(wsb + OFF_WH);
  f16* wouth = (f16*)(wsb + OFF_WOUTH);
  f16* xh = (f16*)(wsb + OFF_XH);
  float* kv = (float*)(wsb + OFF_KV);
  float* den = (float*)(wsb + OFF_DEN);

  k_init<<<768, 256, 0, stream>>>(w_qkv, w_out, wh, wouth, kv);
  k_transpose<<<dim3(64, 4, 16), 256, 0, stream>>>(x, xh);
  k_kv<<<dim3(32, 16), 1024, 0, stream>>>(xh, wh, kv, den);
  k_fused2<<<dim3(32, 16), 1024, 0, stream>>>(xh, wh, wouth, kv, den, ln_g, ln_b, out);
}